// Round 2
// baseline (190.251 us; speedup 1.0000x reference)
//
#include <hip/hip_runtime.h>

#define BATCH 16
#define CH    16
#define HH    128
#define WW    128
#define NC    8            // n_convs
#define TR    8            // output rows per band
#define BPB   2            // bands per block
#define HR    (TR + 2)     // 10 halo rows
#define FW    (WW + 2)     // 130 halo cols
#define NELEM (HR * FW)    // 1300 staged elements per band
#define NSTG  ((NELEM + 255) / 256)   // 6 staging slots per thread

// ---------------------------------------------------------------------------
// Prep kernel: fold spline_scaler into cheby coeffs once, store to workspace.
// ws layout: float4 wgt[72]   ([tap*8+j] = (bw, W1*s, W2*s, W3*s))
//            float  bias[8]   (at ws+288 floats)
// Main kernel then reads these with wave-uniform constant indices -> compiler
// emits s_load_dwordx4 (scalar K$ path). This removes the 72 broadcast
// ds_read_b128 per thread per band that were 2/3 of all LDS traffic, frees
// the LDS port for feature reads, and costs zero VGPRs.
// ---------------------------------------------------------------------------
__global__ void prep_weights(const float* __restrict__ cheby,   // (8,9,4)
                             const float* __restrict__ bwt,     // (8,9)
                             const float* __restrict__ scl,     // (8,9)
                             float* __restrict__ ws)
{
    const int tid = threadIdx.x;         // 0..127
    if (tid < 72) {
        int i = tid >> 3;                // tap 0..8
        int j = tid & 7;                 // conv 0..7
        float s = scl[j * 9 + i];
        ((float4*)ws)[tid] = make_float4(bwt[j * 9 + i],
                                         cheby[(j * 9 + i) * 4 + 1] * s,
                                         cheby[(j * 9 + i) * 4 + 2] * s,
                                         cheby[(j * 9 + i) * 4 + 3] * s);
    } else if (tid < 80) {
        int j = tid - 72;
        float b = 0.f;
        #pragma unroll
        for (int i = 0; i < 9; ++i)
            b += (cheby[(j * 9 + i) * 4 + 0] - cheby[(j * 9 + i) * 4 + 2]) * scl[j * 9 + i];
        ws[288 + j] = b;                 // bias_j absorbs T0 and the +1 of f2
    }
}

// Per-element features: f0=silu(v), f1=tanh(v), f2=2t^2 (=T2+1), f3=T3=4t^3-3t.
// Features are exactly (0,0,0,0) at v=0 -> zero padding handled by feat(0)=0.
__global__ __launch_bounds__(256, 5)
void kan_conv_kernel(const float* __restrict__ x,
                     const float* __restrict__ wb,      // ws: 72 float4 + 8 bias
                     float* __restrict__ out)           // (16,128,128,128)
{
    __shared__ float4 feat[HR][FW];      // 20,800 B (only LDS user now)

    const int tid   = threadIdx.x;       // 0..255
    const int bz    = blockIdx.y;        // plane = b*CH + c
    const int band0 = blockIdx.x * (TR * BPB);

    const float* xp = x + (size_t)bz * HH * WW;
    const float4* __restrict__ wq = (const float4*)wb;  // uniform -> s_load
    const float*  __restrict__ bp = wb + 288;           // bias, uniform

    // ---- issue band-0 staging loads back-to-back into registers ----
    float v[NSTG];
    #pragma unroll
    for (int k = 0; k < NSTG; ++k) {
        int idx = tid + 256 * k;
        int row = idx / FW;              // magic-mul div, cheap
        int col = idx - row * FW;
        int gh  = band0 + row - 1;
        int gw  = col - 1;
        float nv = 0.f;
        if (idx < NELEM && (unsigned)gh < (unsigned)HH && (unsigned)gw < (unsigned)WW)
            nv = xp[gh * WW + gw];       // 4B/lane coalesced
        v[k] = nv;
    }

    for (int bb = 0; bb < BPB; ++bb) {
        const int band = band0 + bb * TR;

        // ---- features from prefetched registers -> LDS ----
        // write stride = 16 B/lane -> canonical conflict-free b128 LDS pattern
        #pragma unroll
        for (int k = 0; k < NSTG; ++k) {
            int idx = tid + 256 * k;
            if (idx < NELEM) {
                int row = idx / FW;
                int col = idx - row * FW;
                float val = v[k];
                float e1 = __expf(val);
                float e2 = e1 * e1;                               // exp(2v)
                float sg = 1.f - __builtin_amdgcn_rcpf(1.f + e1); // sigmoid(v)
                float t  = 1.f - 2.f * __builtin_amdgcn_rcpf(e2 + 1.f); // tanh(v)
                float f2 = 2.f * t * t;                           // T2 + 1
                float f3 = 2.f * t * (f2 - 1.f) - t;              // T3
                feat[row][col] = make_float4(val * sg, t, f2, f3);
            }
        }
        __syncthreads();

        // ---- prefetch next band's x while this band's conv runs ----
        if (bb + 1 < BPB) {
            const int nb = band + TR;
            #pragma unroll
            for (int k = 0; k < NSTG; ++k) {
                int idx = tid + 256 * k;
                int row = idx / FW;
                int col = idx - row * FW;
                int gh  = nb + row - 1;
                int gw  = col - 1;
                float nv = 0.f;
                if (idx < NELEM && (unsigned)gh < (unsigned)HH && (unsigned)gw < (unsigned)WW)
                    nv = xp[gh * WW + gw];
                v[k] = nv;
            }
        }

        // ---- conv: thread owns col c, rows r0+2s (s=0..3); taps unrolled ----
        const int c  = tid & 127;            // 0..127
        const int r0 = tid >> 7;             // 0..1

        float acc[4][NC];                    // 32 VGPRs
        #pragma unroll
        for (int s = 0; s < 4; ++s)
            #pragma unroll
            for (int j = 0; j < NC; ++j)
                acc[s][j] = bp[j];           // s_load'd bias, SGPR broadcast

        #pragma unroll
        for (int dr = 0; dr < 3; ++dr) {
            #pragma unroll
            for (int dc = 0; dc < 3; ++dc) {
                float4 f[4];
                #pragma unroll
                for (int s = 0; s < 4; ++s)
                    f[s] = feat[r0 + 2 * s + dr][c + dc];   // 16B/lane: conflict-free
                #pragma unroll
                for (int j = 0; j < NC; ++j) {
                    float4 w = wq[(dr * 3 + dc) * NC + j];  // uniform -> s_load_dwordx4
                    #pragma unroll
                    for (int s = 0; s < 4; ++s) {
                        acc[s][j] += w.x * f[s].x;
                        acc[s][j] += w.y * f[s].y;
                        acc[s][j] += w.z * f[s].z;
                        acc[s][j] += w.w * f[s].w;
                    }
                }
            }
        }

        // ---- store: each wave writes 64 consecutive floats (256B contiguous) ----
        float* op = out + (size_t)(bz * NC) * HH * WW + (size_t)(band + r0) * WW + c;
        #pragma unroll
        for (int j = 0; j < NC; ++j)
            #pragma unroll
            for (int s = 0; s < 4; ++s)
                op[(size_t)j * HH * WW + s * 2 * WW] = acc[s][j];

        __syncthreads();   // feat[] reuse guard for next band
    }
}

extern "C" void kernel_launch(void* const* d_in, const int* in_sizes, int n_in,
                              void* d_out, int out_size, void* d_ws, size_t ws_size,
                              hipStream_t stream) {
    const float* x     = (const float*)d_in[0];
    const float* cheby = (const float*)d_in[1];
    const float* bwt   = (const float*)d_in[2];
    const float* scl   = (const float*)d_in[3];
    float* out = (float*)d_out;
    float* ws  = (float*)d_ws;           // needs 1184 B

    hipLaunchKernelGGL(prep_weights, dim3(1), dim3(128), 0, stream,
                       cheby, bwt, scl, ws);

    dim3 grid(HH / (TR * BPB), BATCH * CH);  // 8 x 256 = 2048 blocks
    dim3 block(256);
    hipLaunchKernelGGL(kan_conv_kernel, grid, block, 0, stream, x, ws, out);
}

// Round 3
// 161.749 us; speedup vs baseline: 1.1762x; 1.1762x over previous
//
#include <hip/hip_runtime.h>

#define BATCH 16
#define CH    16
#define HH    128
#define WW    128
#define NC    8            // n_convs
#define TR    8            // output rows per band
#define BPB   4            // bands per block (persistent over 4 bands)
#define HR    (TR + 2)     // 10 halo rows
#define FW    (WW + 2)     // 130 halo cols
#define NELEM (HR * FW)    // 1300 staged elements per band
#define NSTG  ((NELEM + 255) / 256)   // 6 staging slots per thread

// Compiler-only fence: pins memory-op code motion without emitting waitcnts.
#define CFENCE asm volatile("" ::: "memory")

// Per-element features: f0=silu(v), f1=tanh(v), f2=2t^2 (=T2+1), f3=T3=4t^3-3t.
// bias_j = sum_i (W0 - W2)[j,i] absorbs T0 and the +1 shift of f2, so features
// are exactly (0,0,0,0) at v=0 -> zero padding handled by feat(0)=0.
//
// Round-4 change (revert R2's global-weight experiment — it regressed to
// ~107 us kernel: uniform global loads don't scalarize, re-issued per tap):
// weights back in LDS (same-address b128 broadcast is cheap). New lever:
// __syncthreads() forces `s_waitcnt vmcnt(0) lgkmcnt(0)` before s_barrier,
// so every band convoyed on a FULL drain of 32 stores/thread + in-flight
// prefetch. Replace with raw s_barrier + minimal waits:
//   barrier A (featwrite->conv):  lgkmcnt(0) only — stores/prefetch fly on
//   barrier B (feat reuse guard): no waitcnt — conv's ds_reads are consumed
//                                 by FMAs before any wave reaches it
// Stores drain under the NEXT band's compute; vmcnt never hits 0 in-loop.
__global__ __launch_bounds__(256, 4)
void kan_conv_kernel(const float* __restrict__ x,
                     const float* __restrict__ cheby,   // (8,9,4)
                     const float* __restrict__ bwt,     // (8,9)
                     const float* __restrict__ scl,     // (8,9)
                     float* __restrict__ out)           // (16,128,128,128)
{
    __shared__ float4 feat[HR][FW];      // 20,800 B
    __shared__ float4 wgt[9 * NC];       // [tap*8 + j] = (bw, W1, W2, W3)
    __shared__ float  bias[NC];

    const int tid   = threadIdx.x;       // 0..255
    const int bz    = blockIdx.y;        // plane = b*CH + c
    const int band0 = blockIdx.x * (TR * BPB);

    const float* xp = x + (size_t)bz * HH * WW;

    // ---- stage combined weights (once per 4 bands) ----
    if (tid < 9 * NC) {
        int j = tid / 9, i = tid % 9;
        float s = scl[j * 9 + i];
        wgt[i * NC + j] = make_float4(bwt[j * 9 + i],
                                      cheby[(j * 9 + i) * 4 + 1] * s,
                                      cheby[(j * 9 + i) * 4 + 2] * s,
                                      cheby[(j * 9 + i) * 4 + 3] * s);
    } else if (tid >= 128 && tid < 128 + NC) {
        int j = tid - 128;
        float b = 0.f;
        #pragma unroll
        for (int i = 0; i < 9; ++i)
            b += (cheby[(j * 9 + i) * 4 + 0] - cheby[(j * 9 + i) * 4 + 2]) * scl[j * 9 + i];
        bias[j] = b;
    }

    // ---- issue band-0 staging loads back-to-back into registers ----
    float v[NSTG];
    #pragma unroll
    for (int k = 0; k < NSTG; ++k) {
        int idx = tid + 256 * k;
        int row = idx / FW;              // magic-mul div, cheap
        int col = idx - row * FW;
        int gh  = band0 + row - 1;
        int gw  = col - 1;
        float nv = 0.f;
        if (idx < NELEM && (unsigned)gh < (unsigned)HH && (unsigned)gw < (unsigned)WW)
            nv = xp[gh * WW + gw];       // 4B/lane coalesced
        v[k] = nv;
    }

    for (int bb = 0; bb < BPB; ++bb) {
        const int band = band0 + bb * TR;

        // ---- feat[] reuse guard: barrier WITHOUT any vm/lgkm drain ----
        // (each wave's conv ds_reads were consumed by its FMAs already;
        //  previous band's stores + this band's prefetch stay in flight)
        if (bb) { CFENCE; __builtin_amdgcn_s_barrier(); CFENCE; }

        // ---- features from prefetched registers -> LDS ----
        // write stride = 16 B/lane -> canonical conflict-free b128 LDS pattern
        #pragma unroll
        for (int k = 0; k < NSTG; ++k) {
            int idx = tid + 256 * k;
            if (idx < NELEM) {
                int row = idx / FW;
                int col = idx - row * FW;
                float val = v[k];
                float e1 = __expf(val);
                float e2 = e1 * e1;                               // exp(2v)
                float sg = 1.f - __builtin_amdgcn_rcpf(1.f + e1); // sigmoid(v)
                float t  = 1.f - 2.f * __builtin_amdgcn_rcpf(e2 + 1.f); // tanh(v)
                float f2 = 2.f * t * t;                           // T2 + 1
                float f3 = 2.f * t * (f2 - 1.f) - t;              // T3
                feat[row][col] = make_float4(val * sg, t, f2, f3);
            }
        }

        // ---- barrier A: LDS writes visible; do NOT drain vmcnt ----
        asm volatile("s_waitcnt lgkmcnt(0)" ::: "memory");
        __builtin_amdgcn_s_barrier();
        CFENCE;

        // ---- prefetch next band's x while this band's conv runs ----
        if (bb + 1 < BPB) {
            const int nb = band + TR;
            #pragma unroll
            for (int k = 0; k < NSTG; ++k) {
                int idx = tid + 256 * k;
                int row = idx / FW;
                int col = idx - row * FW;
                int gh  = nb + row - 1;
                int gw  = col - 1;
                float nv = 0.f;
                if (idx < NELEM && (unsigned)gh < (unsigned)HH && (unsigned)gw < (unsigned)WW)
                    nv = xp[gh * WW + gw];
                v[k] = nv;
            }
        }

        // ---- conv: thread owns col c, rows r0+2s (s=0..3); taps unrolled ----
        const int c  = tid & 127;            // 0..127
        const int r0 = tid >> 7;             // 0..1

        float acc[4][NC];                    // 32 VGPRs — fits, no spill
        #pragma unroll
        for (int s = 0; s < 4; ++s)
            #pragma unroll
            for (int j = 0; j < NC; ++j)
                acc[s][j] = bias[j];

        #pragma unroll
        for (int dr = 0; dr < 3; ++dr) {
            #pragma unroll
            for (int dc = 0; dc < 3; ++dc) {
                float4 f[4];
                #pragma unroll
                for (int s = 0; s < 4; ++s)
                    f[s] = feat[r0 + 2 * s + dr][c + dc];   // 16B/lane: conflict-free
                #pragma unroll
                for (int j = 0; j < NC; ++j) {
                    float4 w = wgt[(dr * 3 + dc) * NC + j]; // uniform LDS broadcast
                    #pragma unroll
                    for (int s = 0; s < 4; ++s) {
                        acc[s][j] += w.x * f[s].x;
                        acc[s][j] += w.y * f[s].y;
                        acc[s][j] += w.z * f[s].z;
                        acc[s][j] += w.w * f[s].w;
                    }
                }
            }
        }

        // ---- store: each wave writes 64 consecutive floats (256B contiguous);
        //      drains in the background under the next band's work ----
        float* op = out + (size_t)(bz * NC) * HH * WW + (size_t)(band + r0) * WW + c;
        #pragma unroll
        for (int j = 0; j < NC; ++j)
            #pragma unroll
            for (int s = 0; s < 4; ++s)
                op[(size_t)j * HH * WW + s * 2 * WW] = acc[s][j];
    }
}

extern "C" void kernel_launch(void* const* d_in, const int* in_sizes, int n_in,
                              void* d_out, int out_size, void* d_ws, size_t ws_size,
                              hipStream_t stream) {
    const float* x     = (const float*)d_in[0];
    const float* cheby = (const float*)d_in[1];
    const float* bwt   = (const float*)d_in[2];
    const float* scl   = (const float*)d_in[3];
    float* out = (float*)d_out;

    dim3 grid(HH / (TR * BPB), BATCH * CH);  // 4 x 256 = 1024 persistent blocks
    dim3 block(256);
    hipLaunchKernelGGL(kan_conv_kernel, grid, block, 0, stream, x, cheby, bwt, scl, out);
}